// Round 11
// baseline (345.089 us; speedup 1.0000x reference)
//
#include <hip/hip_runtime.h>

// LengthRegulator — DIAGNOSTIC build v11 (REP=4, plain stores).
// Six variants sit in a 263.7-271.8us plateau; composite floor says ~241-250
// should be possible. The only copy-pass slope ever measured (56.5us) was on
// the NT-store variant; this run measures the PLAIN-store slope on the best
// structure (v10 tri-path). Validity: per-XCD write set/pass = 29MB >> 4MB L2,
// so idempotent re-passes are NOT L2-absorbed -> all 4 passes hit HBM and the
// slope is the true copy-pass cost. Pre-registered: slope=(dur-264)/3;
// slope<=46 -> declare roofline; slope>=50 -> attack store path.

#define BB 64
#define LL 256
#define DD 512
#define TT 1792
#define D4 (DD / 4)          // 128 float4 per row
#define TILE 64              // frames per block; TT = 28 * TILE exact
#define NBT (TT / TILE)      // 28 t-blocks per b
#define NBLK (BB * NBT)      // 1792 blocks
#define REP 4                // diagnostic: copy phase repeated (idempotent)

typedef float f32x4 __attribute__((ext_vector_type(4)));

__global__ __launch_bounds__(256) void length_regulator_kernel(
    const f32x4* __restrict__ x4,       // [B, L, D4]
    const int*   __restrict__ dur,      // [B, L]
    const int*   __restrict__ maxlen,   // [1]
    float*       __restrict__ out)      // [B*T*D + 1]
{
    __shared__ int wsum[4];
    __shared__ int idx_s[TILE];
    const int tid = threadIdx.x;

    // XCD-locality swizzle: XCD k owns b in [8k, 8k+8).
    const int bid  = blockIdx.x;
    const int virt = (bid & 7) * (NBLK / 8) + (bid >> 3);
    const int b    = virt / NBT;
    const int t0   = (virt % NBT) * TILE;

    // --- inclusive scan of durations: wave shuffle scan + 4-wave combine ---
    // ALPHA = 1.0 -> round(d * 1.0) == d
    int d = dur[b * LL + tid];
    int c = d;
    #pragma unroll
    for (int off = 1; off < 64; off <<= 1) {
        int u = __shfl_up(c, off, 64);
        if ((tid & 63) >= off) c += u;
    }
    if (tid < TILE) idx_s[tid] = -1;          // -1 = "zero frame"
    if ((tid & 63) == 63) wsum[tid >> 6] = c; // wave totals
    __syncthreads();
    int total;
    {
        const int s0 = wsum[0], s1 = wsum[1], s2 = wsum[2], s3 = wsum[3];
        const int wid = tid >> 6;
        total = s0 + s1 + s2 + s3;
        c += (wid > 0 ? s0 : 0) + (wid > 1 ? s1 : 0) + (wid > 2 ? s2 : 0);
        // all-zero row: d[0] = 1 -> cum[j] = 1 for all j
        if (total == 0) { c = 1; d = (tid == 0) ? 1 : 0; total = 1; }
    }

    // --- scatter: thread j stamps idx over [c-d, c) ∩ [t0, t0+TILE) ---
    {
        const int lo = max(c - d, t0);
        const int hi = min(c, t0 + TILE);
        for (int t = lo; t < hi; ++t) idx_s[t - t0] = tid;
    }
    __syncthreads();

    // --- copy phase, repeated REP times (idempotent; diagnostic only) ---
    const int nd    = min(max(total - t0, 0), TILE);  // data frames in tile
    const int group = tid >> 7;   // 0..1
    const int lane  = tid & 127;  // float4 index within row
    const f32x4 z   = (f32x4)(0.f);
    const f32x4* __restrict__ xrow = x4 + (size_t)b * LL * D4;
    f32x4* __restrict__ outb = (f32x4*)out + ((size_t)b * TT + t0) * D4;

    #pragma unroll 1
    for (int rep = 0; rep < REP; ++rep) {
        #pragma unroll
        for (int itb = 0; itb < TILE / 2; itb += 4) {
            const int ta = (itb + 0) * 2 + group;
            const int tb = (itb + 1) * 2 + group;
            const int tc = (itb + 2) * 2 + group;
            const int td = (itb + 3) * 2 + group;
            if (td < nd) {
                f32x4 va = xrow[idx_s[ta] * D4 + lane];
                f32x4 vb = xrow[idx_s[tb] * D4 + lane];
                f32x4 vc = xrow[idx_s[tc] * D4 + lane];
                f32x4 ve = xrow[idx_s[td] * D4 + lane];
                outb[ta * D4 + lane] = va;
                outb[tb * D4 + lane] = vb;
                outb[tc * D4 + lane] = vc;
                outb[td * D4 + lane] = ve;
            } else if (ta >= nd) {
                outb[ta * D4 + lane] = z;
                outb[tb * D4 + lane] = z;
                outb[tc * D4 + lane] = z;
                outb[td * D4 + lane] = z;
            } else {
                const int ia = idx_s[ta];
                const int ib = idx_s[tb];
                const int ic = idx_s[tc];
                const int ie = idx_s[td];
                f32x4 va = xrow[max(ia, 0) * D4 + lane];
                f32x4 vb = xrow[max(ib, 0) * D4 + lane];
                f32x4 vc = xrow[max(ic, 0) * D4 + lane];
                f32x4 ve = xrow[max(ie, 0) * D4 + lane];
                va = (ia >= 0) ? va : z;
                vb = (ib >= 0) ? vb : z;
                vc = (ic >= 0) ? vc : z;
                ve = (ie >= 0) ? ve : z;
                outb[ta * D4 + lane] = va;
                outb[tb * D4 + lane] = vb;
                outb[tc * D4 + lane] = vc;
                outb[td * D4 + lane] = ve;
            }
        }
        // compiler-level memory barrier: keep every pass's stores live.
        asm volatile("" ::: "memory");
    }

    // --- output 1: max_length as float, one thread writes it ---
    if (virt == 0 && tid == 0) {
        out[(size_t)BB * TT * DD] = (float)maxlen[0];
    }
}

extern "C" void kernel_launch(void* const* d_in, const int* in_sizes, int n_in,
                              void* d_out, int out_size, void* d_ws, size_t ws_size,
                              hipStream_t stream) {
    const f32x4* x4  = (const f32x4*)d_in[0];
    const int*   dur = (const int*)d_in[1];
    const int*   ml  = (const int*)d_in[2];
    float*       out = (float*)d_out;

    length_regulator_kernel<<<dim3(NBLK), dim3(256), 0, stream>>>(x4, dur, ml, out);
}

// Round 12
// 264.970 us; speedup vs baseline: 1.3024x; 1.3024x over previous
//
#include <hip/hip_runtime.h>

// LengthRegulator: expand x[B,L,D] along L per integer durations into out[B,T,D].
// B=64, L=256, D=512, T=max_length=1792. Out: (out [B,T,D] f32, max_length).
//
// FINAL (revert to best-measured v5, Round 6: 263.7us).
// Session ledger (dur_us = kernel + ~196us measured harness floor):
//   v5  (this)            263.7   <- best
//   v10 tri-path          264.0   (tie/noise)
//   v7  dedupe+shflscan   266.0
//   v6  two-kernel split  267.5
//   v0  binary search     270.4
//   v8  TILE=128          270.1
//   v2b NT stores         271.8
// Diagnostics (R5/R11 REP=4): marginal copy pass = 27us at 6.6 TB/s HBM
// write (= fill-proven ceiling); NT-store path = 4.16 TB/s (why v2b lost);
// REP=1 kernel ~66.5us = 37us compulsory HBM writes + ~30us ramp/cold-cache
// intercept that 6 structural variants could not move (263.7-271.8 band).
// Structure: LDS scatter (no per-frame searchsorted), wave-uniform idx read,
// batch-4 independent clamped loads + selects, plain stores (L2 writeback),
// XCD-locality swizzle (XCD k owns b in [8k,8k+8) -> 4MB x-panel per L2).

#define BB 64
#define LL 256
#define DD 512
#define TT 1792
#define D4 (DD / 4)          // 128 float4 per row
#define TILE 64              // frames per block; TT = 28 * TILE exact
#define NBT (TT / TILE)      // 28 t-blocks per b
#define NBLK (BB * NBT)      // 1792 blocks

typedef float f32x4 __attribute__((ext_vector_type(4)));

__global__ __launch_bounds__(256) void length_regulator_kernel(
    const f32x4* __restrict__ x4,       // [B, L, D4]
    const int*   __restrict__ dur,      // [B, L]
    const int*   __restrict__ maxlen,   // [1]
    float*       __restrict__ out)      // [B*T*D + 1]
{
    __shared__ int cum[LL];
    __shared__ int idx_s[TILE];
    const int tid = threadIdx.x;

    // XCD-locality swizzle: XCD k owns b in [8k, 8k+8).
    const int bid  = blockIdx.x;
    const int virt = (bid & 7) * (NBLK / 8) + (bid >> 3);
    const int b    = virt / NBT;
    const int t0   = (virt % NBT) * TILE;

    // --- inclusive scan of durations for row b (Hillis-Steele, 8 steps) ---
    // ALPHA = 1.0 -> round(d * 1.0) == d
    cum[tid] = dur[b * LL + tid];
    if (tid < TILE) idx_s[tid] = -1;  // -1 = "zero frame" (t >= total)
    __syncthreads();
    #pragma unroll
    for (int off = 1; off < LL; off <<= 1) {
        int v = (tid >= off) ? cum[tid - off] : 0;
        __syncthreads();
        cum[tid] += v;
        __syncthreads();
    }
    // all-zero row: d[0] = 1 -> cum[j] = 1 for all j
    if (cum[LL - 1] == 0) cum[tid] = 1;
    __syncthreads();

    // --- scatter: thread j stamps its phoneme index over [cum[j-1], cum[j]) ---
    // Reproduces searchsorted(cum, t, 'right'). O(duration) <= 7 LDS writes.
    {
        const int end   = cum[tid];
        const int start = (tid > 0) ? cum[tid - 1] : 0;
        const int lo = max(start, t0);
        const int hi = min(end, t0 + TILE);
        for (int t = lo; t < hi; ++t) idx_s[t - t0] = tid;
    }
    __syncthreads();

    // --- copy: 2 groups x 128 lanes; one D-row per group per iter ---
    // Batch-4: 4 independent loads in flight before 4 stores (all indices
    // compile-time after full unroll -> registers, no scratch).
    const int group = tid >> 7;   // 0..1
    const int lane  = tid & 127;  // float4 index within row
    const f32x4 z   = (f32x4)(0.f);
    const f32x4* __restrict__ xrow = x4 + (size_t)b * LL * D4;
    f32x4* __restrict__ outb = (f32x4*)out + ((size_t)b * TT + t0) * D4;

    #pragma unroll
    for (int itb = 0; itb < TILE / 2; itb += 4) {
        const int ta = (itb + 0) * 2 + group;
        const int tb = (itb + 1) * 2 + group;
        const int tc = (itb + 2) * 2 + group;
        const int td = (itb + 3) * 2 + group;
        const int ia = idx_s[ta];
        const int ib = idx_s[tb];
        const int ic = idx_s[tc];
        const int ie = idx_s[td];
        f32x4 va = xrow[max(ia, 0) * D4 + lane];
        f32x4 vb = xrow[max(ib, 0) * D4 + lane];
        f32x4 vc = xrow[max(ic, 0) * D4 + lane];
        f32x4 ve = xrow[max(ie, 0) * D4 + lane];
        va = (ia >= 0) ? va : z;
        vb = (ib >= 0) ? vb : z;
        vc = (ic >= 0) ? vc : z;
        ve = (ie >= 0) ? ve : z;
        outb[ta * D4 + lane] = va;
        outb[tb * D4 + lane] = vb;
        outb[tc * D4 + lane] = vc;
        outb[td * D4 + lane] = ve;
    }

    // --- output 1: max_length as float, one thread writes it ---
    if (virt == 0 && tid == 0) {
        out[(size_t)BB * TT * DD] = (float)maxlen[0];
    }
}

extern "C" void kernel_launch(void* const* d_in, const int* in_sizes, int n_in,
                              void* d_out, int out_size, void* d_ws, size_t ws_size,
                              hipStream_t stream) {
    const f32x4* x4  = (const f32x4*)d_in[0];
    const int*   dur = (const int*)d_in[1];
    const int*   ml  = (const int*)d_in[2];
    float*       out = (float*)d_out;

    length_regulator_kernel<<<dim3(NBLK), dim3(256), 0, stream>>>(x4, dur, ml, out);
}